// Round 7
// baseline (256.493 us; speedup 1.0000x reference)
//
#include <hip/hip_runtime.h>
#include <hip/hip_fp16.h>
#include <math.h>

// Kobayashi dendrite single timestep, B=4, H=W=2048, fp32, periodic BCs.
// Round 10: tempr via LDS bulk staging. Post-mortem r7/r9: 2-cells/thread cut
// VALUBusy 57->45% but dur flat at 85us -> NOT issue-bound. Little's law:
// phase-3 tempr loads kept only ~100B/wave in flight (need ~400B) ->
// latency-bound at ~half of achievable HBM BW. Fix: stage tempr fp32 tile
// [34][68] in phase 1 (coalesced float2 bulk loads, issued with phi staging ->
// full MLP); phase 3 reads tempr from LDS with rolling registers. LDS 28.3KB
// -> 5 blocks/CU (62% occ) -- fine once latency is bulk-hidden.
// Rounds 11-12: byte-identical resubmissions (broker GPUAcquisitionTimeout;
// this kernel has never been measured).

#define Bz 4
#define Hd 2048
#define Wd 2048
#define TX 64
#define TY 32
#define PW 72          // phi tile cols: cells -4..67 (x halo 4 for alignment)
#define PH 36          // phi tile rows: cells -2..33
#define PW2 (PW/2)     // 36 half2 per phi row
#define QW 68          // Q cols 0..67 <-> cells -2..65 (cell c at qc=c+2, even)
#define QH 34          // Q rows <-> cell rows -1..32
#define STW 68         // tempr tile cols: c=0..67 <-> cells -2..65
#define STH 34         // tempr tile rows: r=0..33 <-> cell rows -1..32

#define INVD2   1111.11111111111f      // 1/0.03^2
#define K1      277.777777777778f      // (1/(2*0.03))^2  (raw-diff fold)
#define DT_TAU  0.333333333333333f     // 1e-4 / 3e-4
#define DTc     1e-4f
#define KAPPAc  1.8f
#define EPSB    0.01f
#define DELTAc  0.02f
#define ANISOc  6.0f
#define A_PI    0.2864788975654116f    // 0.9/pi
#define GAMMAc  10.0f
#define TEQc    1.0f
#define C6T0    0.3623577544766736f    // cos(1.2)
#define S6T0    0.9320390859672263f    // sin(1.2)
#define PI_2    1.5707963267948966f
#define SC      65536.0f               // fp16 scale for prod/eps^2
#define ISC     (1.0f/65536.0f)

// prod from RAW diffs (1/(2d) cancels in theta; folded into K1 at use).
__device__ __forceinline__ void prodc(float dx, float dy,
                                      float& p1s, float& p2s, float& e2s)
{
    float dx2 = dx * dx;
    float r2  = fmaf(dy, dy, dx2);
    float cn  = fmaf(-dy, dy, dx2);
    float irr = __builtin_amdgcn_rcpf(fmaxf(r2, 1e-20f));
    float c2  = cn * irr;
    float s2  = 2.0f * dx * dy * irr;
    float c22 = c2 * c2;
    float s22 = s2 * s2;
    float c6  = c2 * fmaf(4.0f, c22, -3.0f);
    float s6  = s2 * fmaf(-4.0f, s22, 3.0f);
    float cosA = fmaf(c6, C6T0, s6 * S6T0);
    float sinA = fmaf(s6, C6T0, -c6 * S6T0);
    float eps  = fmaf(EPSB * DELTAc, cosA, EPSB);
    float eesc = eps * (-EPSB * ANISOc * DELTAc * SC) * sinA;
    p1s = eesc * dx;
    p2s = -eesc * dy;
    e2s = eps * eps * SC;
}

// atan(g), g in (0,10]; deg-7 odd minimax on [0,1] + rcp fold. |err|<=6.3e-4.
__device__ __forceinline__ float atan_fast(float g) {
    float r  = __builtin_amdgcn_rcpf(g);
    float a  = fminf(g, r);
    float a2 = a * a;
    float p  = a * fmaf(a2, fmaf(a2, 0.079331f, -0.288679f), 0.995354f);
    return (g <= 1.0f) ? p : PI_2 - p;
}

// read 2 adjacent (p1,p2) half2 pairs as one b64
__device__ __forceinline__ void ldq2(const __half2* p,
                                     float& f1a, float& f2a,
                                     float& f1b, float& f2b)
{
    uint2 v = *reinterpret_cast<const uint2*>(p);
    __half2 a = *reinterpret_cast<__half2*>(&v.x);
    __half2 b = *reinterpret_cast<__half2*>(&v.y);
    f1a = __low2float(a); f2a = __high2float(a);
    f1b = __low2float(b); f2b = __high2float(b);
}

__global__ __launch_bounds__(256, 8) void dendrite_step(
    const float* __restrict__ phi, const float* __restrict__ tempr,
    float* __restrict__ out_phi, float* __restrict__ out_tempr)
{
    __shared__ __half2 sphi2[PH * PW2];   // 5184 B
    __shared__ __half2 spk[QH * QW];      // (p1,p2)*SC per Q col, 9248 B
    __shared__ __half  se2[QH * QW];      // eps^2*SC, 4624 B
    __shared__ float   st[STH * STW];     // tempr fp32 tile, 9248 B (tot 28304)

    const int tid = threadIdx.x;
    const int x0 = blockIdx.x * TX;
    const int y0 = blockIdx.y * TY;
    const int base = blockIdx.z * (Hd * Wd);

    // ---- Phase 1a: stage phi tile (x range x0-4 .. x0+67) as fp16 ----
    for (int i = tid; i < PH * PW2; i += 256) {
        int r = i / PW2;
        int c2 = i - r * PW2;
        int gy = (y0 + r - 2) & (Hd - 1);
        int gx = (x0 + 2 * c2 - 4) & (Wd - 1);
        float2 v = *(const float2*)(phi + base + gy * Wd + gx);
        sphi2[i] = __floats2half2_rn(v.x, v.y);
    }
    // ---- Phase 1b: stage tempr tile fp32 (rows -1..32, cols -2..65) ----
    for (int i = tid; i < STH * (STW / 2); i += 256) {
        int r = i / (STW / 2);
        int c2 = i - r * (STW / 2);
        int gy = (y0 + r - 1) & (Hd - 1);
        int gx = (x0 + 2 * c2 - 2) & (Wd - 1);
        float2 v = *(const float2*)(tempr + base + gy * Wd + gx);
        *(float2*)(st + r * STW + 2 * c2) = v;
    }
    __syncthreads();

    // ---- Phase 2: Q col pairs (2j,2j+1), j=0..33, rows r=0..33 ----
    // Q col qc <-> cell col qc-2 <-> phi LDS col qc+2.
    for (int i = tid; i < QH * (QW / 2); i += 256) {
        int r = i / (QW / 2);
        int j = i - r * (QW / 2);
        int rowc = (r + 1) * PW2 + j;
        __half2 P0 = sphi2[rowc];            // phi cols 2j, 2j+1
        __half2 P1 = sphi2[rowc + 1];        // 2j+2, 2j+3
        __half2 P2 = sphi2[rowc + 2];        // 2j+4, 2j+5
        __half2 U  = sphi2[rowc - PW2 + 1];  // row above, cols 2j+2,2j+3
        __half2 D  = sphi2[rowc + PW2 + 1];  // row below

        float dx0 = __high2float(P1) - __high2float(P0); // col 2j+3 - 2j+1
        float dx1 = __low2float(P2)  - __low2float(P1);  // col 2j+4 - 2j+2
        float dy0 = __low2float(D)   - __low2float(U);
        float dy1 = __high2float(D)  - __high2float(U);

        float p1a, p2a, e2a, p1b, p2b, e2b;
        prodc(dx0, dy0, p1a, p2a, e2a);
        prodc(dx1, dy1, p1b, p2b, e2b);

        int q = r * QW + 2 * j;
        spk[q]     = __floats2half2_rn(p1a, p2a);
        spk[q + 1] = __floats2half2_rn(p1b, p2b);
        *reinterpret_cast<__half2*>(se2 + q) = __floats2half2_rn(e2a, e2b);
    }
    __syncthreads();

    // ---- Phase 3: 2 cols x 4 rows per thread, rolling registers ----
    const int tx2 = tid & 31;
    const int tg  = tid >> 5;
    const int ys  = tg * 4;
    const int c0  = tx2 * 2;            // first cell col in tile
    const int qc0 = c0 + 2;             // Q col of cell0 (even)
    const int pctr = (c0 + 4) >> 1;     // half2 index of phi center pair
    const int gx0 = x0 + c0;

    // phi rolling (rows: up = cell y-1 -> LDS ys+1, center -> ys+2)
    float pm0, pm1, pc0, pc1;
    {
        __half2 a = sphi2[(ys + 1) * PW2 + pctr];
        __half2 b = sphi2[(ys + 2) * PW2 + pctr];
        pm0 = __low2float(a); pm1 = __high2float(a);
        pc0 = __low2float(b); pc1 = __high2float(b);
    }

    // p1/p2 rolling: s1m = p1 @ Q row ys; s1c,p2c = @ Q row ys+1
    float s1m0 = __low2float(spk[ys * QW + qc0]);
    float s1m1 = __low2float(spk[ys * QW + qc0 + 1]);
    float s1c0, p2c0, s1c1, p2c1;
    ldq2(spk + (ys + 1) * QW + qc0, s1c0, p2c0, s1c1, p2c1);

    // tempr rolling from LDS tile. Cell row yy <-> st row yy+1; cell col cc
    // <-> st col cc+2. tm = center pair @ cell ys-1; tc* = row ys; tn* = ys+1.
    float tm0, tm1, tcl, tcc0, tcc1, tcr, tnl, tnc0, tnc1, tnr;
    {
        const float* r0 = st + ys * STW + c0;         // st row ys = cell ys-1
        float2 t = *(const float2*)(r0 + 2);
        tm0 = t.x; tm1 = t.y;
        const float* r1 = r0 + STW;                   // cell row ys
        tcl = r1[1];
        float2 tc = *(const float2*)(r1 + 2);
        tcc0 = tc.x; tcc1 = tc.y;
        tcr = r1[4];
        const float* r2 = r1 + STW;                   // cell row ys+1
        tnl = r2[1];
        float2 tn = *(const float2*)(r2 + 2);
        tnc0 = tn.x; tnc1 = tn.y;
        tnr = r2[4];
    }

    #pragma unroll
    for (int k = 0; k < 4; ++k) {
        int y = ys + k;
        int qrow = y + 1;
        int prow = y + 2;

        __half2 hpp = sphi2[(prow + 1) * PW2 + pctr];
        __half2 hL  = sphi2[prow * PW2 + pctr - 1];
        __half2 hR  = sphi2[prow * PW2 + pctr + 1];
        float pp0 = __low2float(hpp), pp1 = __high2float(hpp);
        float pl  = __high2float(hL);   // cell col c0-1
        float pr  = __low2float(hR);    // cell col c0+2

        float lap0 = (pl  + pc1 + pm0 + pp0 - 4.0f * pc0) * INVD2;
        float lap1 = (pc0 + pr  + pm1 + pp1 - 4.0f * pc1) * INVD2;

        // next Q row: p1 -> s1p (term1), p2 -> next-iter center
        float s1p0, p2n0, s1p1, p2n1;
        ldq2(spk + (qrow + 1) * QW + qc0, s1p0, p2n0, s1p1, p2n1);

        float sp2l = __high2float(spk[qrow * QW + qc0 - 1]);  // p2 @ cell c0-1
        float sp2r = __high2float(spk[qrow * QW + qc0 + 2]);  // p2 @ cell c0+2

        __half2 he2 = *reinterpret_cast<const __half2*>(se2 + qrow * QW + qc0);
        float e20 = __low2float(he2) * ISC;
        float e21 = __high2float(he2) * ISC;

        float t120 = (s1p0 - s1m0 + p2c1 - sp2l) * (K1 * ISC);
        float t121 = (s1p1 - s1m1 + sp2r - p2c0) * (K1 * ISC);

        float lt0 = (tcl  + tcc1 + tm0 + tnc0 - 4.0f * tcc0) * INVD2;
        float lt1 = (tcc0 + tcr  + tm1 + tnc1 - 4.0f * tcc1) * INVD2;

        float mm0 = A_PI * atan_fast(GAMMAc * (TEQc - tcc0));
        float mm1 = A_PI * atan_fast(GAMMAc * (TEQc - tcc1));

        float dphi0 = DT_TAU * (t120 + e20 * lap0
                                + pc0 * (1.0f - pc0) * (pc0 - 0.5f + mm0));
        float dphi1 = DT_TAU * (t121 + e21 * lap1
                                + pc1 * (1.0f - pc1) * (pc1 - 0.5f + mm1));

        int gidx = base + (y0 + y) * Wd + gx0;
        *(float2*)(out_phi + gidx) =
            make_float2(pc0 + dphi0, pc1 + dphi1);
        *(float2*)(out_tempr + gidx) =
            make_float2(fmaf(KAPPAc, dphi0, fmaf(DTc, lt0, tcc0)),
                        fmaf(KAPPAc, dphi1, fmaf(DTc, lt1, tcc1)));

        // roll phi / Q
        pm0 = pc0; pm1 = pc1; pc0 = pp0; pc1 = pp1;
        s1m0 = s1c0; s1m1 = s1c1; s1c0 = s1p0; s1c1 = s1p1;
        p2c0 = p2n0; p2c1 = p2n1;
        // roll tempr, refill tn* from LDS (st row y+3 = cell row y+2)
        tm0 = tcc0; tm1 = tcc1;
        tcl = tnl; tcc0 = tnc0; tcc1 = tnc1; tcr = tnr;
        if (k < 3) {
            const float* rn = st + (ys + k + 3) * STW + c0;
            tnl = rn[1];
            float2 t2 = *(const float2*)(rn + 2);
            tnc0 = t2.x; tnc1 = t2.y;
            tnr = rn[4];
        }
    }
}

extern "C" void kernel_launch(void* const* d_in, const int* in_sizes, int n_in,
                              void* d_out, int out_size, void* d_ws, size_t ws_size,
                              hipStream_t stream) {
    const float* phi = (const float*)d_in[0];
    const float* tempr = (const float*)d_in[1];
    float* out_phi = (float*)d_out;
    float* out_tempr = out_phi + (size_t)Bz * Hd * Wd;

    dim3 grid(Wd / TX, Hd / TY, Bz);
    dendrite_step<<<grid, 256, 0, stream>>>(phi, tempr, out_phi, out_tempr);
}

// Round 8
// 236.453 us; speedup vs baseline: 1.0848x; 1.0848x over previous
//
#include <hip/hip_runtime.h>
#include <hip/hip_fp16.h>
#include <math.h>

// Kobayashi dendrite single timestep, B=4, H=W=2048, fp32, periodic BCs.
// Round 13: 64x16 tiles (TY 32->16), r7 structure otherwise unchanged.
// Evidence: r6/r7/r10 show dur tracks occupancy (85us@73%, 85@72, 102@50,
// elasticity ~0.55) while instruction count and phase-3 MLP don't move time
// -> convoy/concurrency-bound. r7 sat exactly at the 8x19.5KB LDS cliff;
// halving the tile (LDS ~10.4KB) makes occupancy wave-cap-limited with
// headroom, doubles block count (better residency fill, shorter barrier
// convoys, decorrelated blocks). Tempr stays as r7: rolling global loads.

#define Bz 4
#define Hd 2048
#define Wd 2048
#define TX 64
#define TY 16
#define PW 72          // phi tile cols: cells -4..67 (x halo 4 for alignment)
#define PH 20          // phi tile rows: cells -2..17
#define PW2 (PW/2)     // 36 half2 per phi row
#define QW 68          // Q cols 0..67 <-> cells -2..65 (cell c at qc=c+2, even)
#define QH 18          // Q rows <-> cell rows -1..16

#define INVD2   1111.11111111111f      // 1/0.03^2
#define K1      277.777777777778f      // (1/(2*0.03))^2  (raw-diff fold)
#define DT_TAU  0.333333333333333f     // 1e-4 / 3e-4
#define DTc     1e-4f
#define KAPPAc  1.8f
#define EPSB    0.01f
#define DELTAc  0.02f
#define ANISOc  6.0f
#define A_PI    0.2864788975654116f    // 0.9/pi
#define GAMMAc  10.0f
#define TEQc    1.0f
#define C6T0    0.3623577544766736f    // cos(1.2)
#define S6T0    0.9320390859672263f    // sin(1.2)
#define PI_2    1.5707963267948966f
#define SC      65536.0f               // fp16 scale for prod/eps^2
#define ISC     (1.0f/65536.0f)

// prod from RAW diffs (1/(2d) cancels in theta; folded into K1 at use).
__device__ __forceinline__ void prodc(float dx, float dy,
                                      float& p1s, float& p2s, float& e2s)
{
    float dx2 = dx * dx;
    float r2  = fmaf(dy, dy, dx2);
    float cn  = fmaf(-dy, dy, dx2);
    float irr = __builtin_amdgcn_rcpf(fmaxf(r2, 1e-20f));
    float c2  = cn * irr;
    float s2  = 2.0f * dx * dy * irr;
    float c22 = c2 * c2;
    float s22 = s2 * s2;
    float c6  = c2 * fmaf(4.0f, c22, -3.0f);
    float s6  = s2 * fmaf(-4.0f, s22, 3.0f);
    float cosA = fmaf(c6, C6T0, s6 * S6T0);
    float sinA = fmaf(s6, C6T0, -c6 * S6T0);
    float eps  = fmaf(EPSB * DELTAc, cosA, EPSB);
    float eesc = eps * (-EPSB * ANISOc * DELTAc * SC) * sinA;
    p1s = eesc * dx;
    p2s = -eesc * dy;
    e2s = eps * eps * SC;
}

// atan(g), g in (0,10]; deg-7 odd minimax on [0,1] + rcp fold. |err|<=6.3e-4.
__device__ __forceinline__ float atan_fast(float g) {
    float r  = __builtin_amdgcn_rcpf(g);
    float a  = fminf(g, r);
    float a2 = a * a;
    float p  = a * fmaf(a2, fmaf(a2, 0.079331f, -0.288679f), 0.995354f);
    return (g <= 1.0f) ? p : PI_2 - p;
}

// read 2 adjacent (p1,p2) half2 pairs as one b64
__device__ __forceinline__ void ldq2(const __half2* p,
                                     float& f1a, float& f2a,
                                     float& f1b, float& f2b)
{
    uint2 v = *reinterpret_cast<const uint2*>(p);
    __half2 a = *reinterpret_cast<__half2*>(&v.x);
    __half2 b = *reinterpret_cast<__half2*>(&v.y);
    f1a = __low2float(a); f2a = __high2float(a);
    f1b = __low2float(b); f2b = __high2float(b);
}

__global__ __launch_bounds__(256, 8) void dendrite_step(
    const float* __restrict__ phi, const float* __restrict__ tempr,
    float* __restrict__ out_phi, float* __restrict__ out_tempr)
{
    __shared__ __half2 sphi2[PH * PW2];   // 2880 B
    __shared__ __half2 spk[QH * QW];      // (p1,p2)*SC per Q col, 4896 B
    __shared__ __half  se2[QH * QW];      // eps^2*SC, 2448 B  (total ~10.2 KB)

    const int tid = threadIdx.x;
    const int x0 = blockIdx.x * TX;
    const int y0 = blockIdx.y * TY;
    const int base = blockIdx.z * (Hd * Wd);

    // ---- Phase 1: stage phi tile (x range x0-4 .. x0+67) as fp16 ----
    for (int i = tid; i < PH * PW2; i += 256) {
        int r = i / PW2;
        int c2 = i - r * PW2;
        int gy = (y0 + r - 2) & (Hd - 1);
        int gx = (x0 + 2 * c2 - 4) & (Wd - 1);
        float2 v = *(const float2*)(phi + base + gy * Wd + gx);
        sphi2[i] = __floats2half2_rn(v.x, v.y);
    }
    __syncthreads();

    // ---- Phase 2: Q col pairs (2j,2j+1), j=0..33, rows r=0..17 ----
    // Q col qc <-> cell col qc-2 <-> phi LDS col qc+2.
    for (int i = tid; i < QH * (QW / 2); i += 256) {
        int r = i / (QW / 2);
        int j = i - r * (QW / 2);
        int rowc = (r + 1) * PW2 + j;
        __half2 P0 = sphi2[rowc];            // phi cols 2j, 2j+1
        __half2 P1 = sphi2[rowc + 1];        // 2j+2, 2j+3
        __half2 P2 = sphi2[rowc + 2];        // 2j+4, 2j+5
        __half2 U  = sphi2[rowc - PW2 + 1];  // row above, cols 2j+2,2j+3
        __half2 D  = sphi2[rowc + PW2 + 1];  // row below

        float dx0 = __high2float(P1) - __high2float(P0); // col 2j+3 - 2j+1
        float dx1 = __low2float(P2)  - __low2float(P1);  // col 2j+4 - 2j+2
        float dy0 = __low2float(D)   - __low2float(U);
        float dy1 = __high2float(D)  - __high2float(U);

        float p1a, p2a, e2a, p1b, p2b, e2b;
        prodc(dx0, dy0, p1a, p2a, e2a);
        prodc(dx1, dy1, p1b, p2b, e2b);

        int q = r * QW + 2 * j;
        spk[q]     = __floats2half2_rn(p1a, p2a);
        spk[q + 1] = __floats2half2_rn(p1b, p2b);
        *reinterpret_cast<__half2*>(se2 + q) = __floats2half2_rn(e2a, e2b);
    }
    __syncthreads();

    // ---- Phase 3: 2 cols x 2 rows per thread, rolling registers ----
    const int tx2 = tid & 31;
    const int tg  = tid >> 5;
    const int ys  = tg * 2;
    const int c0  = tx2 * 2;            // first cell col in tile
    const int qc0 = c0 + 2;             // Q col of cell0 (even)
    const int pctr = (c0 + 4) >> 1;     // half2 index of phi center pair
    const int gx0 = x0 + c0;
    const int gxm = (gx0 - 1) & (Wd - 1);
    const int gxp = (gx0 + 2) & (Wd - 1);

    // phi rolling (rows: up = cell ys-1 -> LDS ys+1, center -> ys+2)
    float pm0, pm1, pc0, pc1;
    {
        __half2 a = sphi2[(ys + 1) * PW2 + pctr];
        __half2 b = sphi2[(ys + 2) * PW2 + pctr];
        pm0 = __low2float(a); pm1 = __high2float(a);
        pc0 = __low2float(b); pc1 = __high2float(b);
    }

    // p1/p2 rolling: s1m = p1 @ Q row ys; s1c,p2c = @ Q row ys+1
    float s1m0 = __low2float(spk[ys * QW + qc0]);
    float s1m1 = __low2float(spk[ys * QW + qc0 + 1]);
    float s1c0, p2c0, s1c1, p2c1;
    ldq2(spk + (ys + 1) * QW + qc0, s1c0, p2c0, s1c1, p2c1);

    // tempr pipeline (float2 centers, scalar sides), as r7
    float tm0, tm1;
    {
        float2 t = *(const float2*)(tempr + base + ((y0 + ys - 1) & (Hd - 1)) * Wd + gx0);
        tm0 = t.x; tm1 = t.y;
    }
    int rb0 = base + (y0 + ys) * Wd;
    float tcl = tempr[rb0 + gxm];
    float2 tc0v = *(const float2*)(tempr + rb0 + gx0);
    float tcc0 = tc0v.x, tcc1 = tc0v.y;
    float tcr = tempr[rb0 + gxp];
    int rb1 = base + ((y0 + ys + 1) & (Hd - 1)) * Wd;
    float tnl = tempr[rb1 + gxm];
    float2 tn0v = *(const float2*)(tempr + rb1 + gx0);
    float tnc0 = tn0v.x, tnc1 = tn0v.y;
    float tnr = tempr[rb1 + gxp];

    #pragma unroll
    for (int k = 0; k < 2; ++k) {
        int y = ys + k;
        int qrow = y + 1;
        int prow = y + 2;

        // issue row y+2 tempr loads now (consumed next iteration)
        float t2l = 0.0f, t2c0 = 0.0f, t2c1 = 0.0f, t2r = 0.0f;
        if (k < 1) {
            int rb2 = base + ((y0 + y + 2) & (Hd - 1)) * Wd;
            t2l = tempr[rb2 + gxm];
            float2 t2 = *(const float2*)(tempr + rb2 + gx0);
            t2c0 = t2.x; t2c1 = t2.y;
            t2r = tempr[rb2 + gxp];
        }

        __half2 hpp = sphi2[(prow + 1) * PW2 + pctr];
        __half2 hL  = sphi2[prow * PW2 + pctr - 1];
        __half2 hR  = sphi2[prow * PW2 + pctr + 1];
        float pp0 = __low2float(hpp), pp1 = __high2float(hpp);
        float pl  = __high2float(hL);   // cell col c0-1
        float pr  = __low2float(hR);    // cell col c0+2

        float lap0 = (pl  + pc1 + pm0 + pp0 - 4.0f * pc0) * INVD2;
        float lap1 = (pc0 + pr  + pm1 + pp1 - 4.0f * pc1) * INVD2;

        // next Q row: p1 -> s1p (term1), p2 -> next-iter center
        float s1p0, p2n0, s1p1, p2n1;
        ldq2(spk + (qrow + 1) * QW + qc0, s1p0, p2n0, s1p1, p2n1);

        float sp2l = __high2float(spk[qrow * QW + qc0 - 1]);  // p2 @ cell c0-1
        float sp2r = __high2float(spk[qrow * QW + qc0 + 2]);  // p2 @ cell c0+2

        __half2 he2 = *reinterpret_cast<const __half2*>(se2 + qrow * QW + qc0);
        float e20 = __low2float(he2) * ISC;
        float e21 = __high2float(he2) * ISC;

        float t120 = (s1p0 - s1m0 + p2c1 - sp2l) * (K1 * ISC);
        float t121 = (s1p1 - s1m1 + sp2r - p2c0) * (K1 * ISC);

        float lt0 = (tcl  + tcc1 + tm0 + tnc0 - 4.0f * tcc0) * INVD2;
        float lt1 = (tcc0 + tcr  + tm1 + tnc1 - 4.0f * tcc1) * INVD2;

        float mm0 = A_PI * atan_fast(GAMMAc * (TEQc - tcc0));
        float mm1 = A_PI * atan_fast(GAMMAc * (TEQc - tcc1));

        float dphi0 = DT_TAU * (t120 + e20 * lap0
                                + pc0 * (1.0f - pc0) * (pc0 - 0.5f + mm0));
        float dphi1 = DT_TAU * (t121 + e21 * lap1
                                + pc1 * (1.0f - pc1) * (pc1 - 0.5f + mm1));

        int gidx = base + (y0 + y) * Wd + gx0;
        *(float2*)(out_phi + gidx) =
            make_float2(pc0 + dphi0, pc1 + dphi1);
        *(float2*)(out_tempr + gidx) =
            make_float2(fmaf(KAPPAc, dphi0, fmaf(DTc, lt0, tcc0)),
                        fmaf(KAPPAc, dphi1, fmaf(DTc, lt1, tcc1)));

        // roll
        pm0 = pc0; pm1 = pc1; pc0 = pp0; pc1 = pp1;
        s1m0 = s1c0; s1m1 = s1c1; s1c0 = s1p0; s1c1 = s1p1;
        p2c0 = p2n0; p2c1 = p2n1;
        tm0 = tcc0; tm1 = tcc1;
        tcl = tnl; tcc0 = tnc0; tcc1 = tnc1; tcr = tnr;
        tnl = t2l; tnc0 = t2c0; tnc1 = t2c1; tnr = t2r;
    }
}

extern "C" void kernel_launch(void* const* d_in, const int* in_sizes, int n_in,
                              void* d_out, int out_size, void* d_ws, size_t ws_size,
                              hipStream_t stream) {
    const float* phi = (const float*)d_in[0];
    const float* tempr = (const float*)d_in[1];
    float* out_phi = (float*)d_out;
    float* out_tempr = out_phi + (size_t)Bz * Hd * Wd;

    dim3 grid(Wd / TX, Hd / TY, Bz);
    dendrite_step<<<grid, 256, 0, stream>>>(phi, tempr, out_phi, out_tempr);
}